// Round 1
// baseline (1276.191 us; speedup 1.0000x reference)
//
#include <hip/hip_runtime.h>

#define MEM_DIM 512
#define IN_DIM 1024
#define BATCH 65536
#define N_NODES 100000
#define N_RELS 500

#define BM 64
#define BN 64
#define BK 64
#define LDS_PAD 8
#define LDS_STRIDE (BK + LDS_PAD)  // 72 shorts = 144 B/row (16B-aligned, 4-bank rotation)

typedef __attribute__((ext_vector_type(8))) short short8;
typedef __attribute__((ext_vector_type(4))) float floatx4;

__device__ __forceinline__ unsigned short f2bf(float f) {
    // round-to-nearest-even fp32 -> bf16 (inputs are finite; no NaN handling)
    unsigned int u = __builtin_bit_cast(unsigned int, f);
    u += 0x7FFFu + ((u >> 16) & 1u);
    return (unsigned short)(u >> 16);
}

// ---------------------------------------------------------------------------
// Kernel 1: out[0:N_NODES*512)   = entity_memory * scale
//           out[N_NODES*512:...) = rel_memory    * scale
// scale = t/(t+1) if t > 1 else 1
// ---------------------------------------------------------------------------
__global__ void init_out_kernel(const float* __restrict__ ent,
                                const float* __restrict__ rel,
                                const int* __restrict__ time_p,
                                float* __restrict__ out) {
    const int t = *time_p;
    const float scale = (t > 1) ? (float)t / (float)(t + 1) : 1.0f;
    const long long ENT = (long long)N_NODES * MEM_DIM;               // 51,200,000 (div by 4)
    const long long TOT = ENT + (long long)N_RELS * MEM_DIM;          // 51,456,000
    const long long n4 = TOT / 4;
    long long i4 = (long long)blockIdx.x * blockDim.x + threadIdx.x;
    const long long stride = (long long)gridDim.x * blockDim.x;
    for (; i4 < n4; i4 += stride) {
        long long off = i4 * 4;
        float4 v;
        if (off < ENT) v = *(const float4*)(ent + off);
        else           v = *(const float4*)(rel + (off - ENT));
        v.x *= scale; v.y *= scale; v.z *= scale; v.w *= scale;
        *(float4*)(out + off) = v;
    }
}

// ---------------------------------------------------------------------------
// Kernel 2: C = emb @ W^T (bf16 MFMA), epilogue:
//   atomicAdd(out[row_offset + ids[m]][n], (C[m][n] + bias[n]) * 1/(t+1))
// Block: 256 threads = 4 waves, 64x64 output tile, BK=64 K-tile.
// Wave (w>>1, w&1) owns a 32x32 sub-tile = 2x2 of 16x16x32 MFMA tiles.
// ---------------------------------------------------------------------------
__global__ __launch_bounds__(256)
void gemm_scatter_kernel(const float* __restrict__ emb,   // [BATCH, IN_DIM]
                         const float* __restrict__ W,     // [MEM_DIM, IN_DIM] (row-major = B^T layout)
                         const float* __restrict__ bias,  // [MEM_DIM]
                         const int* __restrict__ ids,     // [BATCH]
                         const int* __restrict__ time_p,
                         float* __restrict__ out,         // [N_NODES+N_RELS, MEM_DIM]
                         int row_offset) {
    __shared__ unsigned short As[BM][LDS_STRIDE];
    __shared__ unsigned short Bs[BN][LDS_STRIDE];

    const int t = *time_p;
    const float inv = 1.0f / (float)(t + 1);

    const int tid  = threadIdx.x;
    const int wave = tid >> 6;
    const int lane = tid & 63;
    const int wm   = (wave >> 1) * 32;
    const int wn   = (wave & 1) * 32;
    const int lo16 = lane & 15;
    const int quad = lane >> 4;

    const int m0 = blockIdx.x * BM;   // batch-row base
    const int n0 = blockIdx.y * BN;   // out-col base

    floatx4 acc[2][2] = {{{0.f,0.f,0.f,0.f},{0.f,0.f,0.f,0.f}},
                         {{0.f,0.f,0.f,0.f},{0.f,0.f,0.f,0.f}}};

    for (int k0 = 0; k0 < IN_DIM; k0 += BK) {
        // Stage 64x64 fp32 -> bf16 into LDS. 1024 float4 slots per tile,
        // 256 threads x 4 slots. slot -> (row = slot>>4, col = (slot&15)*4).
        #pragma unroll
        for (int s = 0; s < 4; ++s) {
            const int slot = tid + s * 256;
            const int r = slot >> 4;
            const int c = (slot & 15) * 4;
            float4 va = *(const float4*)(emb + (long long)(m0 + r) * IN_DIM + k0 + c);
            unsigned int a0 = (unsigned int)f2bf(va.x) | ((unsigned int)f2bf(va.y) << 16);
            unsigned int a1 = (unsigned int)f2bf(va.z) | ((unsigned int)f2bf(va.w) << 16);
            *(uint2*)&As[r][c] = make_uint2(a0, a1);
            float4 vb = *(const float4*)(W + (long long)(n0 + r) * IN_DIM + k0 + c);
            unsigned int b0 = (unsigned int)f2bf(vb.x) | ((unsigned int)f2bf(vb.y) << 16);
            unsigned int b1 = (unsigned int)f2bf(vb.z) | ((unsigned int)f2bf(vb.w) << 16);
            *(uint2*)&Bs[r][c] = make_uint2(b0, b1);
        }
        __syncthreads();

        #pragma unroll
        for (int kk = 0; kk < BK; kk += 32) {
            short8 a[2], b[2];
            #pragma unroll
            for (int i = 0; i < 2; ++i) {
                a[i] = *(const short8*)&As[wm + i * 16 + lo16][kk + quad * 8];
                b[i] = *(const short8*)&Bs[wn + i * 16 + lo16][kk + quad * 8];
            }
            #pragma unroll
            for (int i = 0; i < 2; ++i)
                #pragma unroll
                for (int j = 0; j < 2; ++j)
                    acc[i][j] = __builtin_amdgcn_mfma_f32_16x16x32_bf16(a[i], b[j], acc[i][j], 0, 0, 0);
        }
        __syncthreads();
    }

    // Epilogue: C/D layout col = lane&15, row = quad*4 + reg.
    #pragma unroll
    for (int i = 0; i < 2; ++i) {
        #pragma unroll
        for (int r = 0; r < 4; ++r) {
            const int brow = m0 + wm + i * 16 + quad * 4 + r;
            const long long orow = (long long)(row_offset + ids[brow]);
            #pragma unroll
            for (int j = 0; j < 2; ++j) {
                const int col = n0 + wn + j * 16 + lo16;
                const float val = (acc[i][j][r] + bias[col]) * inv;
                atomicAdd(out + orow * MEM_DIM + col, val);
            }
        }
    }
}

extern "C" void kernel_launch(void* const* d_in, const int* in_sizes, int n_in,
                              void* d_out, int out_size, void* d_ws, size_t ws_size,
                              hipStream_t stream) {
    const float* nodes_emb = (const float*)d_in[0];
    const float* rels_emb  = (const float*)d_in[1];
    const int*   nodes_ids = (const int*)d_in[2];
    const int*   rels_ids  = (const int*)d_in[3];
    const float* ent_mem   = (const float*)d_in[4];
    const float* rel_mem   = (const float*)d_in[5];
    const float* W_node    = (const float*)d_in[6];
    const float* b_node    = (const float*)d_in[7];
    const float* W_rel     = (const float*)d_in[8];
    const float* b_rel     = (const float*)d_in[9];
    const int*   time_p    = (const int*)d_in[10];
    float* out = (float*)d_out;

    // 1) out = scaled concat of memories (must complete before scatter-adds;
    //    same-stream ordering guarantees that).
    init_out_kernel<<<2048, 256, 0, stream>>>(ent_mem, rel_mem, time_p, out);

    // 2) GEMM + scatter for nodes and rels.
    dim3 grid(BATCH / BM, MEM_DIM / BN);  // (1024, 8)
    gemm_scatter_kernel<<<grid, 256, 0, stream>>>(
        nodes_emb, W_node, b_node, nodes_ids, time_p, out, 0);
    gemm_scatter_kernel<<<grid, 256, 0, stream>>>(
        rels_emb, W_rel, b_rel, rels_ids, time_p, out, N_NODES);
}